// Round 3
// baseline (644.090 us; speedup 1.0000x reference)
//
#include <hip/hip_runtime.h>
#include <hip/hip_bf16.h>
#include <math.h>

#define NN 1536
#define TT 10
#define DD 64
#define NHEAD 4
#define HDIM 16
#define PP 1178880   // NN*(NN-1)/2
#define JSPLIT 4
#define JCHUNK (NN / JSPLIT)
#define EROW 132     // padded A-tile row (dwords): 16B-aligned, bank-uniform

// ws layout (float offsets)
#define WS_NODE0 0
#define WS_G1    98304
#define WS_G2    196608
#define WS_PART  294912              // 4*1536*64 (overlaps GI/GJT region, used before them)
#define WS_GI    294912              // 1536*128
#define WS_GJT   491520              // 128*1536
#define WS_W2R   688128              // 4*128*16
#define WS_TXYT  696320              // 20*1536

static __device__ __forceinline__ float dot64(const float* __restrict__ a,
                                              const float* __restrict__ b) {
    float s = 0.f;
#pragma unroll
    for (int c = 0; c < 64; c += 4) {
        float4 av = *reinterpret_cast<const float4*>(a + c);
        float4 bv = *reinterpret_cast<const float4*>(b + c);
        s = fmaf(av.x, bv.x, s);
        s = fmaf(av.y, bv.y, s);
        s = fmaf(av.z, bv.z, s);
        s = fmaf(av.w, bv.w, s);
    }
    return s;
}

// ---------------- Transformer encoder layer, one block per node ----------------
__global__ __launch_bounds__(64) void k_transformer(
    const float* __restrict__ traj,
    const float* __restrict__ wqkv, const float* __restrict__ bqkv,
    const float* __restrict__ wo,   const float* __restrict__ bo,
    const float* __restrict__ g1,   const float* __restrict__ b1,
    const float* __restrict__ fw1,  const float* __restrict__ fb1,
    const float* __restrict__ fw2,  const float* __restrict__ fb2,
    const float* __restrict__ g2,   const float* __restrict__ b2,
    float* __restrict__ node_out)
{
    __shared__ __align__(16) float xs[TT][DD];
    __shared__ __align__(16) float qkvs[TT][3 * DD];
    __shared__ __align__(16) float cs[TT][DD];
    __shared__ __align__(16) float ys[TT][DD];
    __shared__ float mv[TT][2];

    const int n = blockIdx.x, tid = threadIdx.x;
    const float* xg = traj + (size_t)n * TT * DD;

    for (int idx = tid; idx < TT * DD; idx += 64)
        xs[idx / DD][idx % DD] = xg[idx];
    __syncthreads();

    for (int idx = tid; idx < TT * 3 * DD; idx += 64) {
        int t = idx / (3 * DD), o = idx % (3 * DD);
        qkvs[t][o] = bqkv[o] + dot64(&xs[t][0], wqkv + o * DD);
    }
    __syncthreads();

    if (tid < NHEAD * TT) {
        int h = tid / TT, t = tid % TT;
        float sc[TT];
        float mx = -1e30f;
#pragma unroll
        for (int s = 0; s < TT; ++s) {
            float a = 0.f;
#pragma unroll
            for (int d = 0; d < HDIM; ++d)
                a = fmaf(qkvs[t][h * HDIM + d], qkvs[s][DD + h * HDIM + d], a);
            a *= 0.25f;
            sc[s] = a;
            mx = fmaxf(mx, a);
        }
        float den = 0.f;
#pragma unroll
        for (int s = 0; s < TT; ++s) { sc[s] = expf(sc[s] - mx); den += sc[s]; }
        float inv = 1.f / den;
#pragma unroll
        for (int d = 0; d < HDIM; ++d) {
            float a = 0.f;
#pragma unroll
            for (int s = 0; s < TT; ++s)
                a = fmaf(sc[s], qkvs[s][2 * DD + h * HDIM + d], a);
            cs[t][h * HDIM + d] = a * inv;
        }
    }
    __syncthreads();

    for (int idx = tid; idx < TT * DD; idx += 64) {
        int t = idx / DD, o = idx % DD;
        ys[t][o] = xs[t][o] + bo[o] + dot64(&cs[t][0], wo + o * DD);
    }
    __syncthreads();

    if (tid < TT) {
        float m = 0.f;
        for (int c = 0; c < DD; ++c) m += ys[tid][c];
        m *= (1.f / DD);
        float v = 0.f;
        for (int c = 0; c < DD; ++c) { float d = ys[tid][c] - m; v = fmaf(d, d, v); }
        v *= (1.f / DD);
        mv[tid][0] = m;
        mv[tid][1] = rsqrtf(v + 1e-5f);
    }
    __syncthreads();
    for (int idx = tid; idx < TT * DD; idx += 64) {
        int t = idx / DD, o = idx % DD;
        xs[t][o] = (ys[t][o] - mv[t][0]) * mv[t][1] * g1[o] + b1[o];
    }
    __syncthreads();

    for (int idx = tid; idx < TT * DD; idx += 64) {
        int t = idx / DD, p = idx % DD;
        cs[t][p] = fmaxf(fb1[p] + dot64(&xs[t][0], fw1 + p * DD), 0.f);
    }
    __syncthreads();

    for (int idx = tid; idx < TT * DD; idx += 64) {
        int t = idx / DD, o = idx % DD;
        ys[t][o] = xs[t][o] + fb2[o] + dot64(&cs[t][0], fw2 + o * DD);
    }
    __syncthreads();

    if (tid < TT) {
        float m = 0.f;
        for (int c = 0; c < DD; ++c) m += ys[tid][c];
        m *= (1.f / DD);
        float v = 0.f;
        for (int c = 0; c < DD; ++c) { float d = ys[tid][c] - m; v = fmaf(d, d, v); }
        v *= (1.f / DD);
        mv[tid][0] = m;
        mv[tid][1] = rsqrtf(v + 1e-5f);
    }
    __syncthreads();

    if (tid < DD) {
        float acc = 0.f;
#pragma unroll
        for (int t = 0; t < TT; ++t)
            acc += (ys[t][tid] - mv[t][0]) * mv[t][1];
        node_out[n * DD + tid] = acc * g2[tid] * (1.f / TT) + b2[tid];
    }
}

// ---------------- GCN: partial A@X over j-chunk ----------------
__global__ __launch_bounds__(256) void k_gcn_part(
    const float* __restrict__ A, const float* __restrict__ X,
    float* __restrict__ part)
{
    const int tid = threadIdx.x;
    const int r = tid >> 5;
    const int cp = tid & 31;
    const int i = blockIdx.x * 8 + r;
    const int j0 = blockIdx.y * JCHUNK;

    const float* arow = A + (size_t)i * NN + j0;
    const float* xp = X + (size_t)j0 * 64 + 2 * cp;

    float a0 = 0.f, a1 = 0.f;
#pragma unroll 4
    for (int j = 0; j < JCHUNK; ++j) {
        float av = arow[j];
        float2 xv = *reinterpret_cast<const float2*>(xp + (size_t)j * 64);
        a0 = fmaf(av, xv.x, a0);
        a1 = fmaf(av, xv.y, a1);
    }
    float2* op = reinterpret_cast<float2*>(part + ((size_t)blockIdx.y * NN + i) * 64 + 2 * cp);
    *op = make_float2(a0, a1);
}

// ---------------- GCN: reduce partials, apply W^T + bias + relu ----------------
__global__ __launch_bounds__(256) void k_gcn_red(
    const float* __restrict__ part, const float* __restrict__ W,
    const float* __restrict__ b, float* __restrict__ Y)
{
    __shared__ __align__(16) float yrow[4][68];
    const int o = threadIdx.x & 63, r = threadIdx.x >> 6;
    const int i = blockIdx.x * 4 + r;

    float s = 0.f;
#pragma unroll
    for (int jc = 0; jc < JSPLIT; ++jc)
        s += part[((size_t)jc * NN + i) * 64 + o];
    yrow[r][o] = s;
    __syncthreads();

    float z = b[o] + dot64(&yrow[r][0], W + o * 64);
    Y[(size_t)i * 64 + o] = fmaxf(z, 0.f);
}

// ---------------- prep A: gi table (row-major, per-i), bias folded ----------------
__global__ __launch_bounds__(128) void k_prep_a(
    const float* __restrict__ node, const float* __restrict__ e_w1,
    const float* __restrict__ e_b1, float* __restrict__ gi_t)
{
    __shared__ __align__(16) float ns[64];
    const int b = blockIdx.x;
    if (threadIdx.x < 64) ns[threadIdx.x] = node[b * 64 + threadIdx.x];
    __syncthreads();
    const int o = threadIdx.x;
    gi_t[(size_t)b * 128 + o] = e_b1[o] + dot64(ns, e_w1 + o * 138);
}

// ---------------- prep B: gjT (transposed), w2r, txyT ----------------
__global__ __launch_bounds__(256) void k_prep_b(
    const float* __restrict__ node, const float* __restrict__ e_w1,
    const float* __restrict__ e_w2, const float* __restrict__ traj,
    float* __restrict__ gjT, float* __restrict__ w2r, float* __restrict__ txyT)
{
    const int b = blockIdx.x;
    if (b < 128) {
        const int o = b;
        const float* w = e_w1 + o * 138 + 64;
        for (int j = threadIdx.x; j < NN; j += 256)
            gjT[(size_t)o * NN + j] = dot64(node + (size_t)j * 64, w);
    } else if (b == 128) {
        // w2r[mg][o][m] = e_w2[(mg*16+m)*128 + o]
        for (int idx = threadIdx.x; idx < 4 * 128 * 16; idx += 256) {
            int mg = idx >> 11, o = (idx >> 4) & 127, m = idx & 15;
            w2r[idx] = e_w2[(mg * 16 + m) * 128 + o];
        }
    } else {
        const int tc = b - 129;       // 0..19
        const int t = tc >> 1, c = tc & 1;
        for (int j = threadIdx.x; j < NN; j += 256)
            txyT[(size_t)tc * NN + j] = traj[((size_t)j * TT + t) * DD + c];
    }
}

// ---------------- edge predictor: phase-split through LDS ----------------
// grid (NN-1, 24), 256 threads = 4 waves; 64 pairs per block
__global__ __launch_bounds__(256) void k_edge(
    const float* __restrict__ txyT,
    const float* __restrict__ gi_t, const float* __restrict__ gjT,
    const float* __restrict__ e_w1,
    const float* __restrict__ w2r,  const float* __restrict__ e_b2,
    const float* __restrict__ e_w3, const float* __restrict__ e_b3,
    float* __restrict__ out)
{
    __shared__ __align__(16) float As[64][EROW];
    __shared__ float hs[64][11];
    __shared__ float zsh[4][64];

    const int i = blockIdx.x;
    const int jbase = i + 1 + blockIdx.y * 64;
    if (jbase >= NN) return;

    const int tid = threadIdx.x;
    const int lane = tid & 63;
    const int w = __builtin_amdgcn_readfirstlane(tid >> 6);   // wave id 0..3
    const int j = jbase + lane;
    const bool valid = (j < NN);
    const int jj = valid ? j : (NN - 1);
    const int p = i * (NN - 1) - (i * (i - 1)) / 2 + (j - i - 1);

    // ---- phase 0: hist + dmin (wave 0 only) ----
    if (w == 0) {
        float dmin = 3.4e38f;
#pragma unroll
        for (int t = 0; t < 10; ++t) {
            float dx = txyT[(size_t)(2 * t) * NN + i] - txyT[(size_t)(2 * t) * NN + jj];
            float dy = txyT[(size_t)(2 * t + 1) * NN + i] - txyT[(size_t)(2 * t + 1) * NN + jj];
            float d = sqrtf(fmaf(dx, dx, dy * dy));
            dmin = fminf(dmin, d);
            float h = 1.f / (1.f + expf(50.f - 10.f * d));
            hs[lane][t] = h;
            if (valid) out[2 * (size_t)PP + (size_t)p * 10 + t] = h;
        }
        if (valid) out[PP + (size_t)p] = dmin;
    }
    __syncthreads();

    // ---- phase 1: A[pair][o] = relu(gi+b1 + gj + hist.wh), wave w -> o strip ----
    {
        float hist[10];
#pragma unroll
        for (int t = 0; t < 10; ++t) hist[t] = hs[lane][t];
        const float* gi_row = gi_t + (size_t)i * 128;   // uniform -> scalar
        const int o0 = w * 32;
#pragma unroll
        for (int og = 0; og < 32; og += 4) {
            float4 av;
            float* ap = &av.x;
#pragma unroll
            for (int k = 0; k < 4; ++k) {
                const int o = o0 + og + k;
                float a = gi_row[o] + gjT[(size_t)o * NN + jj];
                const float* wh = e_w1 + o * 138 + 128; // uniform -> scalar
#pragma unroll
                for (int t = 0; t < 10; ++t) a = fmaf(hist[t], wh[t], a);
                ap[k] = fmaxf(a, 0.f);
            }
            *reinterpret_cast<float4*>(&As[lane][o0 + og]) = av;
        }
    }
    __syncthreads();

    // ---- phase 2: h2-chunk GEMM from LDS; thread = (pair=lane, mg=w) ----
    float acc[16];
    const float* b2p = e_b2 + w * 16;                    // uniform -> scalar
#pragma unroll
    for (int m = 0; m < 16; ++m) acc[m] = b2p[m];

    const float* w2base = w2r + (size_t)w * 128 * 16;    // uniform -> scalar
    for (int o4 = 0; o4 < 128; o4 += 4) {
        float4 av = *reinterpret_cast<const float4*>(&As[lane][o4]);
#pragma unroll
        for (int k = 0; k < 4; ++k) {
            const float a = (&av.x)[k];
            const float* wv = w2base + (o4 + k) * 16;
#pragma unroll
            for (int m = 0; m < 16; ++m) acc[m] = fmaf(a, wv[m], acc[m]);
        }
    }

    const float* w3 = e_w3 + w * 16;                     // uniform -> scalar
    float z = 0.f;
#pragma unroll
    for (int m = 0; m < 16; ++m) z = fmaf(fmaxf(acc[m], 0.f), w3[m], z);
    zsh[w][lane] = z;
    __syncthreads();

    if (w == 0 && valid) {
        float zt = zsh[0][lane] + zsh[1][lane] + zsh[2][lane] + zsh[3][lane] + e_b3[0];
        out[p] = 1.f / (1.f + expf(-zt));
    }
}

extern "C" void kernel_launch(void* const* d_in, const int* in_sizes, int n_in,
                              void* d_out, int out_size, void* d_ws, size_t ws_size,
                              hipStream_t stream) {
    const float* traj   = (const float*)d_in[0];
    const float* adj    = (const float*)d_in[1];
    const float* w_in   = (const float*)d_in[2];
    const float* b_in   = (const float*)d_in[3];
    const float* w_out  = (const float*)d_in[4];
    const float* b_out  = (const float*)d_in[5];
    const float* ln1g   = (const float*)d_in[6];
    const float* ln1b   = (const float*)d_in[7];
    const float* fw1    = (const float*)d_in[8];
    const float* fb1    = (const float*)d_in[9];
    const float* fw2    = (const float*)d_in[10];
    const float* fb2    = (const float*)d_in[11];
    const float* ln2g   = (const float*)d_in[12];
    const float* ln2b   = (const float*)d_in[13];
    const float* gcn_w  = (const float*)d_in[14];
    const float* gcn_b  = (const float*)d_in[15];
    const float* e_w1   = (const float*)d_in[16];
    const float* e_b1   = (const float*)d_in[17];
    const float* e_w2   = (const float*)d_in[18];
    const float* e_b2   = (const float*)d_in[19];
    const float* e_w3   = (const float*)d_in[20];
    const float* e_b3   = (const float*)d_in[21];

    float* ws    = (float*)d_ws;
    float* node0 = ws + WS_NODE0;
    float* g1b   = ws + WS_G1;
    float* g2b   = ws + WS_G2;
    float* partb = ws + WS_PART;
    float* gi    = ws + WS_GI;
    float* gjT   = ws + WS_GJT;
    float* w2r   = ws + WS_W2R;
    float* txyT  = ws + WS_TXYT;

    k_transformer<<<NN, 64, 0, stream>>>(traj, w_in, b_in, w_out, b_out,
                                         ln1g, ln1b, fw1, fb1, fw2, fb2,
                                         ln2g, ln2b, node0);

    dim3 pgrid(NN / 8, JSPLIT);
    k_gcn_part<<<pgrid, 256, 0, stream>>>(adj, node0, partb);
    k_gcn_red<<<NN / 4, 256, 0, stream>>>(partb, gcn_w, gcn_b, g1b);
    k_gcn_part<<<pgrid, 256, 0, stream>>>(adj, g1b, partb);
    k_gcn_red<<<NN / 4, 256, 0, stream>>>(partb, gcn_w + 4096, gcn_b + 64, g2b);
    k_gcn_part<<<pgrid, 256, 0, stream>>>(adj, g2b, partb);
    k_gcn_red<<<NN / 4, 256, 0, stream>>>(partb, gcn_w + 8192, gcn_b + 128, g1b);

    k_prep_a<<<NN, 128, 0, stream>>>(g1b, e_w1, e_b1, gi);
    k_prep_b<<<149, 256, 0, stream>>>(g1b, e_w1, e_w2, traj, gjT, w2r, txyT);

    dim3 egrid(NN - 1, 24);
    k_edge<<<egrid, 256, 0, stream>>>(txyT, gi, gjT, e_w1, w2r, e_b2,
                                      e_w3, e_b3, (float*)d_out);
}

// Round 4
// 512.606 us; speedup vs baseline: 1.2565x; 1.2565x over previous
//
#include <hip/hip_runtime.h>
#include <hip/hip_bf16.h>
#include <math.h>

#define NN 1536
#define TT 10
#define DD 64
#define NHEAD 4
#define HDIM 16
#define PP 1178880   // NN*(NN-1)/2 = 4605 * 256 exactly
#define JSPLIT 4
#define JCHUNK (NN / JSPLIT)

// ws layout (float offsets)
#define WS_NODE0 0
#define WS_G1    98304
#define WS_G2    196608
#define WS_PART  294912              // 4*1536*64 (overlaps GI/GJT region, used before them)
#define WS_GI    294912              // 1536*128
#define WS_GJT   491520              // 128*1536
#define WS_W2T   688128              // 128*64
#define WS_TXYT  696320              // 20*1536

static __device__ __forceinline__ float dot64(const float* __restrict__ a,
                                              const float* __restrict__ b) {
    float s = 0.f;
#pragma unroll
    for (int c = 0; c < 64; c += 4) {
        float4 av = *reinterpret_cast<const float4*>(a + c);
        float4 bv = *reinterpret_cast<const float4*>(b + c);
        s = fmaf(av.x, bv.x, s);
        s = fmaf(av.y, bv.y, s);
        s = fmaf(av.z, bv.z, s);
        s = fmaf(av.w, bv.w, s);
    }
    return s;
}

// ---------------- Transformer encoder layer, one block (128 thr) per node ----------------
__global__ __launch_bounds__(128) void k_transformer(
    const float* __restrict__ traj,
    const float* __restrict__ wqkv, const float* __restrict__ bqkv,
    const float* __restrict__ wo,   const float* __restrict__ bo,
    const float* __restrict__ g1,   const float* __restrict__ b1,
    const float* __restrict__ fw1,  const float* __restrict__ fb1,
    const float* __restrict__ fw2,  const float* __restrict__ fb2,
    const float* __restrict__ g2,   const float* __restrict__ b2,
    float* __restrict__ node_out)
{
    __shared__ __align__(16) float xs[TT][DD];
    __shared__ __align__(16) float qkvs[TT][3 * DD];
    __shared__ __align__(16) float cs[TT][DD];
    __shared__ __align__(16) float ys[TT][DD];
    __shared__ float mv[TT][2];

    const int n = blockIdx.x, tid = threadIdx.x;
    const float* xg = traj + (size_t)n * TT * DD;

    for (int idx = tid; idx < TT * DD; idx += 128)
        xs[idx / DD][idx % DD] = xg[idx];
    __syncthreads();

    for (int idx = tid; idx < TT * 3 * DD; idx += 128) {
        int t = idx / (3 * DD), o = idx % (3 * DD);
        qkvs[t][o] = bqkv[o] + dot64(&xs[t][0], wqkv + o * DD);
    }
    __syncthreads();

    if (tid < NHEAD * TT) {
        int h = tid / TT, t = tid % TT;
        float sc[TT];
        float mx = -1e30f;
#pragma unroll
        for (int s = 0; s < TT; ++s) {
            float a = 0.f;
#pragma unroll
            for (int d = 0; d < HDIM; ++d)
                a = fmaf(qkvs[t][h * HDIM + d], qkvs[s][DD + h * HDIM + d], a);
            a *= 0.25f;
            sc[s] = a;
            mx = fmaxf(mx, a);
        }
        float den = 0.f;
#pragma unroll
        for (int s = 0; s < TT; ++s) { sc[s] = expf(sc[s] - mx); den += sc[s]; }
        float inv = 1.f / den;
#pragma unroll
        for (int d = 0; d < HDIM; ++d) {
            float a = 0.f;
#pragma unroll
            for (int s = 0; s < TT; ++s)
                a = fmaf(sc[s], qkvs[s][2 * DD + h * HDIM + d], a);
            cs[t][h * HDIM + d] = a * inv;
        }
    }
    __syncthreads();

    for (int idx = tid; idx < TT * DD; idx += 128) {
        int t = idx / DD, o = idx % DD;
        ys[t][o] = xs[t][o] + bo[o] + dot64(&cs[t][0], wo + o * DD);
    }
    __syncthreads();

    if (tid < TT) {
        float m = 0.f;
        for (int c = 0; c < DD; ++c) m += ys[tid][c];
        m *= (1.f / DD);
        float v = 0.f;
        for (int c = 0; c < DD; ++c) { float d = ys[tid][c] - m; v = fmaf(d, d, v); }
        v *= (1.f / DD);
        mv[tid][0] = m;
        mv[tid][1] = rsqrtf(v + 1e-5f);
    }
    __syncthreads();
    for (int idx = tid; idx < TT * DD; idx += 128) {
        int t = idx / DD, o = idx % DD;
        xs[t][o] = (ys[t][o] - mv[t][0]) * mv[t][1] * g1[o] + b1[o];
    }
    __syncthreads();

    for (int idx = tid; idx < TT * DD; idx += 128) {
        int t = idx / DD, p = idx % DD;
        cs[t][p] = fmaxf(fb1[p] + dot64(&xs[t][0], fw1 + p * DD), 0.f);
    }
    __syncthreads();

    for (int idx = tid; idx < TT * DD; idx += 128) {
        int t = idx / DD, o = idx % DD;
        ys[t][o] = xs[t][o] + fb2[o] + dot64(&cs[t][0], fw2 + o * DD);
    }
    __syncthreads();

    if (tid < TT) {
        float m = 0.f;
        for (int c = 0; c < DD; ++c) m += ys[tid][c];
        m *= (1.f / DD);
        float v = 0.f;
        for (int c = 0; c < DD; ++c) { float d = ys[tid][c] - m; v = fmaf(d, d, v); }
        v *= (1.f / DD);
        mv[tid][0] = m;
        mv[tid][1] = rsqrtf(v + 1e-5f);
    }
    __syncthreads();

    if (tid < DD) {
        float acc = 0.f;
#pragma unroll
        for (int t = 0; t < TT; ++t)
            acc += (ys[t][tid] - mv[t][0]) * mv[t][1];
        node_out[n * DD + tid] = acc * g2[tid] * (1.f / TT) + b2[tid];
    }
}

// ---------------- GCN: partial A@X over j-chunk ----------------
__global__ __launch_bounds__(256) void k_gcn_part(
    const float* __restrict__ A, const float* __restrict__ X,
    float* __restrict__ part)
{
    const int tid = threadIdx.x;
    const int r = tid >> 5;
    const int cp = tid & 31;
    const int i = blockIdx.x * 8 + r;
    const int j0 = blockIdx.y * JCHUNK;

    const float* arow = A + (size_t)i * NN + j0;
    const float* xp = X + (size_t)j0 * 64 + 2 * cp;

    float a0 = 0.f, a1 = 0.f;
#pragma unroll 4
    for (int j = 0; j < JCHUNK; ++j) {
        float av = arow[j];
        float2 xv = *reinterpret_cast<const float2*>(xp + (size_t)j * 64);
        a0 = fmaf(av, xv.x, a0);
        a1 = fmaf(av, xv.y, a1);
    }
    float2* op = reinterpret_cast<float2*>(part + ((size_t)blockIdx.y * NN + i) * 64 + 2 * cp);
    *op = make_float2(a0, a1);
}

// ---------------- GCN: reduce partials, apply W^T + bias + relu ----------------
__global__ __launch_bounds__(256) void k_gcn_red(
    const float* __restrict__ part, const float* __restrict__ W,
    const float* __restrict__ b, float* __restrict__ Y)
{
    __shared__ __align__(16) float yrow[4][68];
    const int o = threadIdx.x & 63, r = threadIdx.x >> 6;
    const int i = blockIdx.x * 4 + r;

    float s = 0.f;
#pragma unroll
    for (int jc = 0; jc < JSPLIT; ++jc)
        s += part[((size_t)jc * NN + i) * 64 + o];
    yrow[r][o] = s;
    __syncthreads();

    float z = b[o] + dot64(&yrow[r][0], W + o * 64);
    Y[(size_t)i * 64 + o] = fmaxf(z, 0.f);
}

// ---------------- prep A: gi table (row-major, per-i), bias folded ----------------
__global__ __launch_bounds__(128) void k_prep_a(
    const float* __restrict__ node, const float* __restrict__ e_w1,
    const float* __restrict__ e_b1, float* __restrict__ gi_t)
{
    __shared__ __align__(16) float ns[64];
    const int b = blockIdx.x;
    if (threadIdx.x < 64) ns[threadIdx.x] = node[b * 64 + threadIdx.x];
    __syncthreads();
    const int o = threadIdx.x;
    gi_t[(size_t)b * 128 + o] = e_b1[o] + dot64(ns, e_w1 + o * 138);
}

// ---------------- prep B: gjT (transposed), w2t[o][m], txyT ----------------
__global__ __launch_bounds__(256) void k_prep_b(
    const float* __restrict__ node, const float* __restrict__ e_w1,
    const float* __restrict__ e_w2, const float* __restrict__ traj,
    float* __restrict__ gjT, float* __restrict__ w2t, float* __restrict__ txyT)
{
    const int b = blockIdx.x;
    if (b < 128) {
        const int o = b;
        const float* w = e_w1 + o * 138 + 64;
        for (int j = threadIdx.x; j < NN; j += 256)
            gjT[(size_t)o * NN + j] = dot64(node + (size_t)j * 64, w);
    } else if (b == 128) {
        // w2t[o][m] = e_w2[m*128 + o]
        for (int idx = threadIdx.x; idx < 128 * 64; idx += 256) {
            int o = idx >> 6, m = idx & 63;
            w2t[idx] = e_w2[m * 128 + o];
        }
    } else {
        const int tc = b - 129;       // 0..19
        const int t = tc >> 1, c = tc & 1;
        for (int j = threadIdx.x; j < NN; j += 256)
            txyT[(size_t)tc * NN + j] = traj[((size_t)j * TT + t) * DD + c];
    }
}

// ---------------- edge predictor: 1 thread per pair, flat index, h2 in regs ----------------
// __launch_bounds__(256, 4): 4 waves/EU min -> 128-VGPR budget, no strip-mining
__global__ __launch_bounds__(256, 4) void k_edge(
    const float* __restrict__ txyT,
    const float* __restrict__ gi_t, const float* __restrict__ gjT,
    const float* __restrict__ e_w1,
    const float* __restrict__ w2t,  const float* __restrict__ e_b2,
    const float* __restrict__ e_w3, const float* __restrict__ e_b3,
    float* __restrict__ out)
{
    const int p = blockIdx.x * 256 + threadIdx.x;   // PP = 4605*256 exactly, no tail

    // invert p -> (i, j): S(i) = i*(2N-1-i)/2, exact fp32 sqrt + integer fixup
    const float Df = (float)((2 * NN - 1) * (2 * NN - 1) - 8 * p);
    int i = (int)(((float)(2 * NN - 1) - sqrtf(Df)) * 0.5f);
    i = i < 0 ? 0 : (i > NN - 2 ? NN - 2 : i);
    while (i * (2 * NN - 1 - i) / 2 > p) --i;
    while ((i + 1) * (2 * NN - 2 - i) / 2 <= p) ++i;
    const int j = i + 1 + (p - i * (2 * NN - 1 - i) / 2);

    // hist + dmin
    float hist[10];
    float dmin = 3.4e38f;
#pragma unroll
    for (int t = 0; t < 10; ++t) {
        float dx = txyT[(size_t)(2 * t) * NN + i] - txyT[(size_t)(2 * t) * NN + j];
        float dy = txyT[(size_t)(2 * t + 1) * NN + i] - txyT[(size_t)(2 * t + 1) * NN + j];
        float d = sqrtf(fmaf(dx, dx, dy * dy));
        dmin = fminf(dmin, d);
        hist[t] = 1.f / (1.f + expf(50.f - 10.f * d));
    }

    // L1 + L2 fused: h2[64] resident in VGPRs
    float h2[64];
#pragma unroll
    for (int m = 0; m < 64; ++m) h2[m] = e_b2[m];

#pragma unroll 4
    for (int o = 0; o < 128; ++o) {
        float a = gi_t[(size_t)i * 128 + o] + gjT[(size_t)o * NN + j];
        const float* wh = e_w1 + o * 138 + 128;   // uniform -> scalar path
#pragma unroll
        for (int t = 0; t < 10; ++t) a = fmaf(hist[t], wh[t], a);
        a = fmaxf(a, 0.f);
        const float* w2 = w2t + o * 64;           // uniform -> scalar path
#pragma unroll
        for (int m = 0; m < 64; ++m) h2[m] = fmaf(a, w2[m], h2[m]);
    }

    float z = e_b3[0];
#pragma unroll
    for (int m = 0; m < 64; ++m) z = fmaf(fmaxf(h2[m], 0.f), e_w3[m], z);

    out[p] = 1.f / (1.f + expf(-z));
    out[PP + (size_t)p] = dmin;
    float* hp = out + 2 * (size_t)PP + (size_t)p * 10;
#pragma unroll
    for (int t = 0; t < 10; ++t) hp[t] = hist[t];
}

extern "C" void kernel_launch(void* const* d_in, const int* in_sizes, int n_in,
                              void* d_out, int out_size, void* d_ws, size_t ws_size,
                              hipStream_t stream) {
    const float* traj   = (const float*)d_in[0];
    const float* adj    = (const float*)d_in[1];
    const float* w_in   = (const float*)d_in[2];
    const float* b_in   = (const float*)d_in[3];
    const float* w_out  = (const float*)d_in[4];
    const float* b_out  = (const float*)d_in[5];
    const float* ln1g   = (const float*)d_in[6];
    const float* ln1b   = (const float*)d_in[7];
    const float* fw1    = (const float*)d_in[8];
    const float* fb1    = (const float*)d_in[9];
    const float* fw2    = (const float*)d_in[10];
    const float* fb2    = (const float*)d_in[11];
    const float* ln2g   = (const float*)d_in[12];
    const float* ln2b   = (const float*)d_in[13];
    const float* gcn_w  = (const float*)d_in[14];
    const float* gcn_b  = (const float*)d_in[15];
    const float* e_w1   = (const float*)d_in[16];
    const float* e_b1   = (const float*)d_in[17];
    const float* e_w2   = (const float*)d_in[18];
    const float* e_b2   = (const float*)d_in[19];
    const float* e_w3   = (const float*)d_in[20];
    const float* e_b3   = (const float*)d_in[21];

    float* ws    = (float*)d_ws;
    float* node0 = ws + WS_NODE0;
    float* g1b   = ws + WS_G1;
    float* g2b   = ws + WS_G2;
    float* partb = ws + WS_PART;
    float* gi    = ws + WS_GI;
    float* gjT   = ws + WS_GJT;
    float* w2t   = ws + WS_W2T;
    float* txyT  = ws + WS_TXYT;

    k_transformer<<<NN, 128, 0, stream>>>(traj, w_in, b_in, w_out, b_out,
                                          ln1g, ln1b, fw1, fb1, fw2, fb2,
                                          ln2g, ln2b, node0);

    dim3 pgrid(NN / 8, JSPLIT);
    k_gcn_part<<<pgrid, 256, 0, stream>>>(adj, node0, partb);
    k_gcn_red<<<NN / 4, 256, 0, stream>>>(partb, gcn_w, gcn_b, g1b);
    k_gcn_part<<<pgrid, 256, 0, stream>>>(adj, g1b, partb);
    k_gcn_red<<<NN / 4, 256, 0, stream>>>(partb, gcn_w + 4096, gcn_b + 64, g2b);
    k_gcn_part<<<pgrid, 256, 0, stream>>>(adj, g2b, partb);
    k_gcn_red<<<NN / 4, 256, 0, stream>>>(partb, gcn_w + 8192, gcn_b + 128, g1b);

    k_prep_a<<<NN, 128, 0, stream>>>(g1b, e_w1, e_b1, gi);
    k_prep_b<<<149, 256, 0, stream>>>(g1b, e_w1, e_w2, traj, gjT, w2t, txyT);

    k_edge<<<PP / 256, 256, 0, stream>>>(txyT, gi, gjT, e_w1, w2t, e_b2,
                                         e_w3, e_b3, (float*)d_out);
}

// Round 5
// 440.872 us; speedup vs baseline: 1.4609x; 1.1627x over previous
//
#include <hip/hip_runtime.h>
#include <hip/hip_bf16.h>
#include <math.h>

#define NN 1536
#define TT 10
#define DD 64
#define NHEAD 4
#define HDIM 16
#define PP 1178880   // NN*(NN-1)/2 = 4605 * 256 exactly; = 18420 * 64
#define JSPLIT 4
#define JCHUNK (NN / JSPLIT)

// ws layout (float offsets)
#define WS_NODE0 0
#define WS_G1    98304
#define WS_G2    196608
#define WS_PART  294912              // 4*1536*64 (overlaps GI/GJT region, used before them)
#define WS_GI    294912              // 1536*128
#define WS_GJT   491520              // 128*1536
#define WS_W2F   688128              // 16384 ushort = 8192 float slots
#define WS_TXYT  696320              // 20*1536

using bf16x8 = __attribute__((ext_vector_type(8))) short;
using f32x4  = __attribute__((ext_vector_type(4))) float;

static __device__ __forceinline__ unsigned short f2bf(float f) {
    unsigned int u = __float_as_uint(f);
    unsigned int r = (u + 0x7FFFu + ((u >> 16) & 1u)) >> 16;
    return (unsigned short)r;
}
static __device__ __forceinline__ float bf2f(unsigned short h) {
    return __uint_as_float(((unsigned int)h) << 16);
}

static __device__ __forceinline__ float dot64(const float* __restrict__ a,
                                              const float* __restrict__ b) {
    float s = 0.f;
#pragma unroll
    for (int c = 0; c < 64; c += 4) {
        float4 av = *reinterpret_cast<const float4*>(a + c);
        float4 bv = *reinterpret_cast<const float4*>(b + c);
        s = fmaf(av.x, bv.x, s);
        s = fmaf(av.y, bv.y, s);
        s = fmaf(av.z, bv.z, s);
        s = fmaf(av.w, bv.w, s);
    }
    return s;
}

// ---------------- Transformer encoder layer, one block (128 thr) per node ----------------
__global__ __launch_bounds__(128) void k_transformer(
    const float* __restrict__ traj,
    const float* __restrict__ wqkv, const float* __restrict__ bqkv,
    const float* __restrict__ wo,   const float* __restrict__ bo,
    const float* __restrict__ g1,   const float* __restrict__ b1,
    const float* __restrict__ fw1,  const float* __restrict__ fb1,
    const float* __restrict__ fw2,  const float* __restrict__ fb2,
    const float* __restrict__ g2,   const float* __restrict__ b2,
    float* __restrict__ node_out)
{
    __shared__ __align__(16) float xs[TT][DD];
    __shared__ __align__(16) float qkvs[TT][3 * DD];
    __shared__ __align__(16) float cs[TT][DD];
    __shared__ __align__(16) float ys[TT][DD];
    __shared__ float mv[TT][2];

    const int n = blockIdx.x, tid = threadIdx.x;
    const float* xg = traj + (size_t)n * TT * DD;

    for (int idx = tid; idx < TT * DD; idx += 128)
        xs[idx / DD][idx % DD] = xg[idx];
    __syncthreads();

    for (int idx = tid; idx < TT * 3 * DD; idx += 128) {
        int t = idx / (3 * DD), o = idx % (3 * DD);
        qkvs[t][o] = bqkv[o] + dot64(&xs[t][0], wqkv + o * DD);
    }
    __syncthreads();

    if (tid < NHEAD * TT) {
        int h = tid / TT, t = tid % TT;
        float sc[TT];
        float mx = -1e30f;
#pragma unroll
        for (int s = 0; s < TT; ++s) {
            float a = 0.f;
#pragma unroll
            for (int d = 0; d < HDIM; ++d)
                a = fmaf(qkvs[t][h * HDIM + d], qkvs[s][DD + h * HDIM + d], a);
            a *= 0.25f;
            sc[s] = a;
            mx = fmaxf(mx, a);
        }
        float den = 0.f;
#pragma unroll
        for (int s = 0; s < TT; ++s) { sc[s] = expf(sc[s] - mx); den += sc[s]; }
        float inv = 1.f / den;
#pragma unroll
        for (int d = 0; d < HDIM; ++d) {
            float a = 0.f;
#pragma unroll
            for (int s = 0; s < TT; ++s)
                a = fmaf(sc[s], qkvs[s][2 * DD + h * HDIM + d], a);
            cs[t][h * HDIM + d] = a * inv;
        }
    }
    __syncthreads();

    for (int idx = tid; idx < TT * DD; idx += 128) {
        int t = idx / DD, o = idx % DD;
        ys[t][o] = xs[t][o] + bo[o] + dot64(&cs[t][0], wo + o * DD);
    }
    __syncthreads();

    if (tid < TT) {
        float m = 0.f;
        for (int c = 0; c < DD; ++c) m += ys[tid][c];
        m *= (1.f / DD);
        float v = 0.f;
        for (int c = 0; c < DD; ++c) { float d = ys[tid][c] - m; v = fmaf(d, d, v); }
        v *= (1.f / DD);
        mv[tid][0] = m;
        mv[tid][1] = rsqrtf(v + 1e-5f);
    }
    __syncthreads();
    for (int idx = tid; idx < TT * DD; idx += 128) {
        int t = idx / DD, o = idx % DD;
        xs[t][o] = (ys[t][o] - mv[t][0]) * mv[t][1] * g1[o] + b1[o];
    }
    __syncthreads();

    for (int idx = tid; idx < TT * DD; idx += 128) {
        int t = idx / DD, p = idx % DD;
        cs[t][p] = fmaxf(fb1[p] + dot64(&xs[t][0], fw1 + p * DD), 0.f);
    }
    __syncthreads();

    for (int idx = tid; idx < TT * DD; idx += 128) {
        int t = idx / DD, o = idx % DD;
        ys[t][o] = xs[t][o] + fb2[o] + dot64(&cs[t][0], fw2 + o * DD);
    }
    __syncthreads();

    if (tid < TT) {
        float m = 0.f;
        for (int c = 0; c < DD; ++c) m += ys[tid][c];
        m *= (1.f / DD);
        float v = 0.f;
        for (int c = 0; c < DD; ++c) { float d = ys[tid][c] - m; v = fmaf(d, d, v); }
        v *= (1.f / DD);
        mv[tid][0] = m;
        mv[tid][1] = rsqrtf(v + 1e-5f);
    }
    __syncthreads();

    if (tid < DD) {
        float acc = 0.f;
#pragma unroll
        for (int t = 0; t < TT; ++t)
            acc += (ys[t][tid] - mv[t][0]) * mv[t][1];
        node_out[n * DD + tid] = acc * g2[tid] * (1.f / TT) + b2[tid];
    }
}

// ---------------- GCN: partial A@X over j-chunk ----------------
__global__ __launch_bounds__(256) void k_gcn_part(
    const float* __restrict__ A, const float* __restrict__ X,
    float* __restrict__ part)
{
    const int tid = threadIdx.x;
    const int r = tid >> 5;
    const int cp = tid & 31;
    const int i = blockIdx.x * 8 + r;
    const int j0 = blockIdx.y * JCHUNK;

    const float* arow = A + (size_t)i * NN + j0;
    const float* xp = X + (size_t)j0 * 64 + 2 * cp;

    float a0 = 0.f, a1 = 0.f;
#pragma unroll 4
    for (int j = 0; j < JCHUNK; ++j) {
        float av = arow[j];
        float2 xv = *reinterpret_cast<const float2*>(xp + (size_t)j * 64);
        a0 = fmaf(av, xv.x, a0);
        a1 = fmaf(av, xv.y, a1);
    }
    float2* op = reinterpret_cast<float2*>(part + ((size_t)blockIdx.y * NN + i) * 64 + 2 * cp);
    *op = make_float2(a0, a1);
}

// ---------------- GCN: reduce partials, apply W^T + bias + relu ----------------
__global__ __launch_bounds__(256) void k_gcn_red(
    const float* __restrict__ part, const float* __restrict__ W,
    const float* __restrict__ b, float* __restrict__ Y)
{
    __shared__ __align__(16) float yrow[4][68];
    const int o = threadIdx.x & 63, r = threadIdx.x >> 6;
    const int i = blockIdx.x * 4 + r;

    float s = 0.f;
#pragma unroll
    for (int jc = 0; jc < JSPLIT; ++jc)
        s += part[((size_t)jc * NN + i) * 64 + o];
    yrow[r][o] = s;
    __syncthreads();

    float z = b[o] + dot64(&yrow[r][0], W + o * 64);
    Y[(size_t)i * 64 + o] = fmaxf(z, 0.f);
}

// ---------------- prep A: gi table (row-major, per-i), bias folded ----------------
__global__ __launch_bounds__(128) void k_prep_a(
    const float* __restrict__ node, const float* __restrict__ e_w1,
    const float* __restrict__ e_b1, float* __restrict__ gi_t)
{
    __shared__ __align__(16) float ns[64];
    const int b = blockIdx.x;
    if (threadIdx.x < 64) ns[threadIdx.x] = node[b * 64 + threadIdx.x];
    __syncthreads();
    const int o = threadIdx.x;
    gi_t[(size_t)b * 128 + o] = e_b1[o] + dot64(ns, e_w1 + o * 138);
}

// ---------------- prep B: gjT (transposed), w2f (MFMA B-frags hi/lo), txyT ----------------
__global__ __launch_bounds__(256) void k_prep_b(
    const float* __restrict__ node, const float* __restrict__ e_w1,
    const float* __restrict__ e_w2, const float* __restrict__ traj,
    float* __restrict__ gjT, unsigned short* __restrict__ w2f,
    float* __restrict__ txyT)
{
    const int b = blockIdx.x;
    if (b < 128) {
        const int o = b;
        const float* w = e_w1 + o * 138 + 64;
        for (int j = threadIdx.x; j < NN; j += 256)
            gjT[(size_t)o * NN + j] = dot64(node + (size_t)j * 64, w);
    } else if (b == 128) {
        // w2f[((nt*4+kk)*2+half)*512 + lane*8 + e] = bf16 half of W2[k][n]
        // n = nt*16 + (lane&15); k = kk*32 + (lane>>4)*8 + e; W2[k][n] = e_w2[n*128+k]
        for (int idx = threadIdx.x; idx < 16384; idx += 256) {
            int e = idx & 7, lane = (idx >> 3) & 63;
            int half = (idx >> 9) & 1, kk = (idx >> 10) & 3, nt = (idx >> 12) & 3;
            int n = nt * 16 + (lane & 15);
            int k = kk * 32 + (lane >> 4) * 8 + e;
            float v = e_w2[n * 128 + k];
            unsigned short hi = f2bf(v);
            unsigned short lo = f2bf(v - bf2f(hi));
            w2f[idx] = half ? lo : hi;
        }
    } else {
        const int tc = b - 129;       // 0..19
        const int t = tc >> 1, c = tc & 1;
        for (int j = threadIdx.x; j < NN; j += 256)
            txyT[(size_t)tc * NN + j] = traj[((size_t)j * TT + t) * DD + c];
    }
}

// ---------------- edge predictor: MFMA, 64 pairs/block, 4 waves ----------------
// L1 in fp32 -> bf16 hi/lo split -> 3-term MFMA (Ah*Bh + Ah*Bl + Al*Bh)
__global__ __launch_bounds__(256, 4) void k_edge(
    const float* __restrict__ txyT,
    const float* __restrict__ gi_t, const float* __restrict__ gjT,
    const float* __restrict__ e_w1,
    const unsigned short* __restrict__ w2f, const float* __restrict__ e_b2,
    const float* __restrict__ e_w3, const float* __restrict__ e_b3,
    float* __restrict__ out)
{
    // LDS: A-tiles (swizzled), hist, z-partials
    __shared__ __align__(16) unsigned short Ah[64 * 128];
    __shared__ __align__(16) unsigned short Al[64 * 128];
    __shared__ float hs[10][64];
    __shared__ float zsh[4][64];

    const int tid  = threadIdx.x;
    const int lane = tid & 63;
    const int wv   = __builtin_amdgcn_readfirstlane(tid >> 6);  // wave 0..3
    const int p    = blockIdx.x * 64 + lane;                    // this lane's pair

    // invert p -> (i, j)
    const float Df = (float)((2 * NN - 1) * (2 * NN - 1) - 8 * p);
    int i = (int)(((float)(2 * NN - 1) - sqrtf(Df)) * 0.5f);
    i = i < 0 ? 0 : (i > NN - 2 ? NN - 2 : i);
    while (i * (2 * NN - 1 - i) / 2 > p) --i;
    while ((i + 1) * (2 * NN - 2 - i) / 2 <= p) ++i;
    const int j = i + 1 + (p - i * (2 * NN - 1 - i) / 2);

    // ---- phase 0: wave 0 computes hist + dmin ----
    if (wv == 0) {
        float dmin = 3.4e38f;
#pragma unroll
        for (int t = 0; t < 10; ++t) {
            float dx = txyT[(size_t)(2 * t) * NN + i] - txyT[(size_t)(2 * t) * NN + j];
            float dy = txyT[(size_t)(2 * t + 1) * NN + i] - txyT[(size_t)(2 * t + 1) * NN + j];
            float d = sqrtf(fmaf(dx, dx, dy * dy));
            dmin = fminf(dmin, d);
            float h = 1.f / (1.f + expf(50.f - 10.f * d));
            hs[t][lane] = h;
            out[2 * (size_t)PP + (size_t)p * 10 + t] = h;
        }
        out[PP + (size_t)p] = dmin;
    }
    __syncthreads();

    // ---- phase 1: L1 activations for o-window [32*wv, 32*wv+32), fp32 -> hi/lo bf16 ----
    {
        float hist[10];
#pragma unroll
        for (int t = 0; t < 10; ++t) hist[t] = hs[t][lane];

        const float* giRow = gi_t + (size_t)i * 128 + wv * 32;
        float4 giv[8];
#pragma unroll
        for (int q = 0; q < 8; ++q)
            giv[q] = *reinterpret_cast<const float4*>(giRow + q * 4);
        const float* gif = &giv[0].x;

        unsigned int ahp[16], alp[16];
#pragma unroll
        for (int q = 0; q < 16; ++q) {
            const int o = (wv << 5) + 2 * q;
            float a0 = gif[2 * q]     + gjT[(size_t)o * NN + j];
            float a1 = gif[2 * q + 1] + gjT[(size_t)(o + 1) * NN + j];
            const float* wh0 = e_w1 + o * 138 + 128;        // scalar path
            const float* wh1 = wh0 + 138;
#pragma unroll
            for (int t = 0; t < 10; ++t) {
                a0 = fmaf(hist[t], wh0[t], a0);
                a1 = fmaf(hist[t], wh1[t], a1);
            }
            a0 = fmaxf(a0, 0.f);
            a1 = fmaxf(a1, 0.f);
            unsigned short h0 = f2bf(a0), h1 = f2bf(a1);
            ahp[q] = (unsigned int)h0 | ((unsigned int)h1 << 16);
            unsigned short l0 = f2bf(a0 - bf2f(h0)), l1 = f2bf(a1 - bf2f(h1));
            alp[q] = (unsigned int)l0 | ((unsigned int)l1 << 16);
        }

        // swizzled writes: row = lane, bytes [64*wv + 16*c) ^ ((lane&7)<<4)
        char* ahb = (char*)Ah + lane * 256;
        char* alb = (char*)Al + lane * 256;
#pragma unroll
        for (int c = 0; c < 4; ++c) {
            const int boff = ((wv << 6) + (c << 4)) ^ ((lane & 7) << 4);
            *reinterpret_cast<uint4*>(ahb + boff) = *reinterpret_cast<uint4*>(&ahp[4 * c]);
            *reinterpret_cast<uint4*>(alb + boff) = *reinterpret_cast<uint4*>(&alp[4 * c]);
        }
    }

    // ---- B-frags for m-tile nt = wv (global, L2-hit), issued before barrier ----
    bf16x8 bh[4], bl[4];
#pragma unroll
    for (int kk = 0; kk < 4; ++kk) {
        const unsigned short* bb = w2f + ((size_t)(wv * 4 + kk) * 2) * 512 + lane * 8;
        bh[kk] = *reinterpret_cast<const bf16x8*>(bb);
        bl[kk] = *reinterpret_cast<const bf16x8*>(bb + 512);
    }
    __syncthreads();

    // ---- phase 2: MFMA. wave wv: C[64 pairs][m-tile wv], K = 128 ----
    f32x4 acc[4];
#pragma unroll
    for (int pt = 0; pt < 4; ++pt) acc[pt] = (f32x4){0.f, 0.f, 0.f, 0.f};

    const char* ahr = (const char*)Ah;
    const char* alr = (const char*)Al;
#pragma unroll
    for (int kk = 0; kk < 4; ++kk) {
        const int boff = ((kk << 6) + ((lane >> 4) << 4)) ^ ((lane & 7) << 4);
#pragma unroll
        for (int pt = 0; pt < 4; ++pt) {
            const int row = pt * 16 + (lane & 15);
            bf16x8 afh = *reinterpret_cast<const bf16x8*>(ahr + row * 256 + boff);
            bf16x8 afl = *reinterpret_cast<const bf16x8*>(alr + row * 256 + boff);
            acc[pt] = __builtin_amdgcn_mfma_f32_16x16x32_bf16(afh, bh[kk], acc[pt], 0, 0, 0);
            acc[pt] = __builtin_amdgcn_mfma_f32_16x16x32_bf16(afh, bl[kk], acc[pt], 0, 0, 0);
            acc[pt] = __builtin_amdgcn_mfma_f32_16x16x32_bf16(afl, bh[kk], acc[pt], 0, 0, 0);
        }
    }

    // ---- epilogue: z-partials for m in [16*wv, 16*wv+16) ----
    {
        const int m = wv * 16 + (lane & 15);
        const float w3v = e_w3[m];
        const float b2v = e_b2[m];
#pragma unroll
        for (int pt = 0; pt < 4; ++pt) {
            float zs0 = 0.f, zs1 = 0.f, zs2 = 0.f, zs3 = 0.f;
            zs0 = fmaxf(acc[pt][0] + b2v, 0.f) * w3v;
            zs1 = fmaxf(acc[pt][1] + b2v, 0.f) * w3v;
            zs2 = fmaxf(acc[pt][2] + b2v, 0.f) * w3v;
            zs3 = fmaxf(acc[pt][3] + b2v, 0.f) * w3v;
            // butterfly over the 16-lane col group
#pragma unroll
            for (int msk = 1; msk < 16; msk <<= 1) {
                zs0 += __shfl_xor(zs0, msk);
                zs1 += __shfl_xor(zs1, msk);
                zs2 += __shfl_xor(zs2, msk);
                zs3 += __shfl_xor(zs3, msk);
            }
            if ((lane & 15) == 0) {
                const int pr = pt * 16 + (lane >> 4) * 4;
                zsh[wv][pr]     = zs0;
                zsh[wv][pr + 1] = zs1;
                zsh[wv][pr + 2] = zs2;
                zsh[wv][pr + 3] = zs3;
            }
        }
    }
    __syncthreads();

    if (wv == 0) {
        float z = zsh[0][lane] + zsh[1][lane] + zsh[2][lane] + zsh[3][lane] + e_b3[0];
        out[p] = 1.f / (1.f + expf(-z));
    }
}

extern "C" void kernel_launch(void* const* d_in, const int* in_sizes, int n_in,
                              void* d_out, int out_size, void* d_ws, size_t ws_size,
                              hipStream_t stream) {
    const float* traj   = (const float*)d_in[0];
    const float* adj    = (const float*)d_in[1];
    const float* w_in   = (const float*)d_in[2];
    const float* b_in   = (const float*)d_in[3];
    const float* w_out  = (const float*)d_in[4];
    const float* b_out  = (const float*)d_in[5];
    const float* ln1g   = (const float*)d_in[6];
    const float* ln1b   = (const float*)d_in[7];
    const float* fw1    = (const float*)d_in[8];
    const float* fb1    = (const float*)d_in[9];
    const float* fw2    = (const float*)d_in[10];
    const float* fb2    = (const float*)d_in[11];
    const float* ln2g   = (const float*)d_in[12];
    const float* ln2b   = (const float*)d_in[13];
    const float* gcn_w  = (const float*)d_in[14];
    const float* gcn_b  = (const float*)d_in[15];
    const float* e_w1   = (const float*)d_in[16];
    const float* e_b1   = (const float*)d_in[17];
    const float* e_w2   = (const float*)d_in[18];
    const float* e_b2   = (const float*)d_in[19];
    const float* e_w3   = (const float*)d_in[20];
    const float* e_b3   = (const float*)d_in[21];

    float* ws    = (float*)d_ws;
    float* node0 = ws + WS_NODE0;
    float* g1b   = ws + WS_G1;
    float* g2b   = ws + WS_G2;
    float* partb = ws + WS_PART;
    float* gi    = ws + WS_GI;
    float* gjT   = ws + WS_GJT;
    unsigned short* w2f = (unsigned short*)(ws + WS_W2F);
    float* txyT  = ws + WS_TXYT;

    k_transformer<<<NN, 128, 0, stream>>>(traj, w_in, b_in, w_out, b_out,
                                          ln1g, ln1b, fw1, fb1, fw2, fb2,
                                          ln2g, ln2b, node0);

    dim3 pgrid(NN / 8, JSPLIT);
    k_gcn_part<<<pgrid, 256, 0, stream>>>(adj, node0, partb);
    k_gcn_red<<<NN / 4, 256, 0, stream>>>(partb, gcn_w, gcn_b, g1b);
    k_gcn_part<<<pgrid, 256, 0, stream>>>(adj, g1b, partb);
    k_gcn_red<<<NN / 4, 256, 0, stream>>>(partb, gcn_w + 4096, gcn_b + 64, g2b);
    k_gcn_part<<<pgrid, 256, 0, stream>>>(adj, g2b, partb);
    k_gcn_red<<<NN / 4, 256, 0, stream>>>(partb, gcn_w + 8192, gcn_b + 128, g1b);

    k_prep_a<<<NN, 128, 0, stream>>>(g1b, e_w1, e_b1, gi);
    k_prep_b<<<149, 256, 0, stream>>>(g1b, e_w1, e_w2, traj, gjT, w2f, txyT);

    k_edge<<<PP / 64, 256, 0, stream>>>(txyT, gi, gjT, e_w1, w2f, e_b2,
                                        e_w3, e_b3, (float*)d_out);
}